// Round 3
// baseline (754.467 us; speedup 1.0000x reference)
//
#include <hip/hip_runtime.h>

// AvgPool2d k=3 s=2 VALID. x: (8,64,512,512) fp32 -> out: (8,64,255,255) fp32.
//
// Dense-load / rolling-accumulator / 2-row software pipeline:
//  - Lane i loads float4 at cols 4i and 256+4i (byte 16*i across the wave)
//    -> every global_load_dwordx4 is 100% cache-line dense; one wave covers
//    a full 512-col input row in 2 vector loads.
//  - Window-overlap columns via scalar loads rp[4], rp[260]: same lines the
//    vector loads fetched -> L1 hits. (Lane 63's rp[4] lands on col 256,
//    exactly what its out col 127 needs; rp[260] reads next-row col 0,
//    in-bounds, feeds only the nonexistent out col 255 -> never stored.)
//  - Horizontal 3-sums give out cols {2i, 2i+1, 128+2i, 129+2i} per lane ->
//    full 255-col output row per wave. Plain dword stores (L2 write-merges;
//    nontemporal stores measured slower in round 2).
//  - Vertical: rolling accumulator A = h(2m) over a band of BAND out rows;
//    each input row fetched once per wave (33 rows per 32 unique, +3%).
//  - Explicit 2-row-deep prefetch: next out-row's 2 input rows are issued
//    before the current row's arithmetic/stores -> ~10 VMEM in flight/wave.
//  - Grid: 512 planes x 4 blocks x 4 waves = 16 bands/plane, 2048 blocks
//    = 8 blocks/CU -> 32 waves/CU.

#define IN_H 512
#define IN_W 512
#define OUT_H 255
#define OUT_W 255
#define PLANES 512   // N*C = 8*64
#define BAND 16      // output rows per wave (last band: 15)

struct Row { float4 a, b; float n0, n1; };

__device__ __forceinline__ Row ldrow(const float* __restrict__ rp) {
    Row r;
    r.a  = *(const float4*)rp;          // cols 4i   .. 4i+3
    r.b  = *(const float4*)(rp + 256);  // cols 256+4i .. 256+4i+3
    r.n0 = rp[4];                       // col 4i+4   (L1 hit)
    r.n1 = rp[260];                     // col 256+4i+4 (L1 hit)
    return r;
}

__device__ __forceinline__ float4 hs(const Row& r) {
    float4 h;
    h.x = r.a.x + r.a.y + r.a.z;        // out 2i     : in 4i..4i+2
    h.y = r.a.z + r.a.w + r.n0;         // out 2i+1   : in 4i+2..4i+4
    h.z = r.b.x + r.b.y + r.b.z;        // out 128+2i : in 256+4i..258+4i
    h.w = r.b.z + r.b.w + r.n1;         // out 129+2i : in 258+4i..260+4i
    return h;
}

__global__ __launch_bounds__(256) void KeyedAvgpool2d_kernel(
    const float* __restrict__ in, float* __restrict__ out) {
    const int lane = threadIdx.x & 63;
    const int wv   = threadIdx.x >> 6;
    const int band = blockIdx.x * 4 + wv;   // 0..15
    const int nc   = blockIdx.y;            // plane 0..511

    const int j0 = band * BAND;
    const int j1 = min(j0 + BAND, OUT_H);   // band 15 -> 15 rows

    const float* __restrict__ rp =
        in + (size_t)nc * (IN_H * IN_W) + (size_t)(2 * j0) * IN_W + 4 * lane;
    float* __restrict__ op =
        out + (size_t)nc * (OUT_H * OUT_W) + (size_t)j0 * OUT_W + 2 * lane;

    const float inv9 = 1.0f / 9.0f;
    const bool not63 = (lane != 63);

    // Preamble: row 2*j0 (accumulator) + pipeline rows 2*j0+1, 2*j0+2.
    Row r0 = ldrow(rp);
    Row p1 = ldrow(rp + IN_W);
    Row p2 = ldrow(rp + 2 * IN_W);
    rp += 2 * IN_W;
    float4 A = hs(r0);                  // h(2*j0)

    for (int m = j0; m < j1; ++m) {
        const Row c1 = p1;
        const Row c2 = p2;
        if (m + 1 < j1) {               // prefetch next out-row's input rows
            p1 = ldrow(rp + IN_W);      //   row 2m+3
            p2 = ldrow(rp + 2 * IN_W);  //   row 2m+4 (max touched: 510)
            rp += 2 * IN_W;
        }
        const float4 h1 = hs(c1);       // h(2m+1)
        const float4 h2 = hs(c2);       // h(2m+2)
        op[0]   = (A.x + h1.x + h2.x) * inv9;   // out col 2i
        op[1]   = (A.y + h1.y + h2.y) * inv9;   // out col 2i+1
        op[128] = (A.z + h1.z + h2.z) * inv9;   // out col 128+2i
        if (not63)                              // out col 255 doesn't exist
            op[129] = (A.w + h1.w + h2.w) * inv9;
        op += OUT_W;
        A = h2;                         // h(2(m+1))
    }
}

extern "C" void kernel_launch(void* const* d_in, const int* in_sizes, int n_in,
                              void* d_out, int out_size, void* d_ws, size_t ws_size,
                              hipStream_t stream) {
    const float* x = (const float*)d_in[0];
    float* o = (float*)d_out;

    dim3 block(256, 1, 1);          // 4 waves = 4 bands
    dim3 grid(4, PLANES, 1);        // 4*4 = 16 bands ; 512 planes
    KeyedAvgpool2d_kernel<<<grid, block, 0, stream>>>(x, o);
}